// Round 2
// baseline (8408.614 us; speedup 1.0000x reference)
//
#include <hip/hip_runtime.h>
#include <hip/hip_bf16.h>
#include <math.h>

// ---------------------------------------------------------------------------
// SMN forward. B=512 U=10 L=50 E=200 H=200 V=50000
// Workspace budget ~237 MiB (guarded against ws_size).
// ---------------------------------------------------------------------------

__device__ __forceinline__ float sigm(float x) { return 1.0f / (1.0f + __expf(-x)); }
__device__ __forceinline__ float tanhfast(float x) {
    float e = __expf(2.0f * x);
    return 1.0f - 2.0f / (e + 1.0f);
}

// ---------------------------------------------------------------------------
// Generic C[M,N] = act(A[M,K] @ W[N,K]^T + bias)
// A rows optionally gathered: row m uses A + gidx[m*gstride+goff]*K
// ---------------------------------------------------------------------------
__global__ __launch_bounds__(256)
void gemm_tn(const float* __restrict__ A, const int* __restrict__ gidx,
             int gstride, int goff,
             const float* __restrict__ W, const float* __restrict__ bias,
             float* __restrict__ C, int M, int N, int K, int act)
{
    __shared__ float As[16][64];
    __shared__ float Ws[16][64];
    const int tid = threadIdx.x;
    const int m0 = blockIdx.x * 64;
    const int n0 = blockIdx.y * 64;
    const int lr = tid >> 2;          // 0..63 row loaded by this thread
    const int lk = (tid & 3) << 2;    // 0,4,8,12 k-offset
    const int tx = tid & 15, ty = tid >> 4;

    float acc[4][4];
#pragma unroll
    for (int i = 0; i < 4; ++i)
#pragma unroll
        for (int j = 0; j < 4; ++j) acc[i][j] = 0.0f;

    const int am = m0 + lr;
    const float* arow = nullptr;
    if (am < M) arow = gidx ? (A + (size_t)gidx[(size_t)am * gstride + goff] * K)
                            : (A + (size_t)am * K);
    const int wn = n0 + lr;
    const float* wrow = (wn < N) ? (W + (size_t)wn * K) : nullptr;

    for (int kb = 0; kb < K; kb += 16) {
        const int k = kb + lk;
        float a0 = 0, a1 = 0, a2 = 0, a3 = 0, w0 = 0, w1 = 0, w2 = 0, w3 = 0;
        if (arow) {
            if (k + 3 < K) { float4 v = *(const float4*)(arow + k); a0 = v.x; a1 = v.y; a2 = v.z; a3 = v.w; }
            else { if (k < K) a0 = arow[k]; if (k + 1 < K) a1 = arow[k + 1]; if (k + 2 < K) a2 = arow[k + 2]; }
        }
        if (wrow) {
            if (k + 3 < K) { float4 v = *(const float4*)(wrow + k); w0 = v.x; w1 = v.y; w2 = v.z; w3 = v.w; }
            else { if (k < K) w0 = wrow[k]; if (k + 1 < K) w1 = wrow[k + 1]; if (k + 2 < K) w2 = wrow[k + 2]; }
        }
        __syncthreads();
        As[lk + 0][lr] = a0; As[lk + 1][lr] = a1; As[lk + 2][lr] = a2; As[lk + 3][lr] = a3;
        Ws[lk + 0][lr] = w0; Ws[lk + 1][lr] = w1; Ws[lk + 2][lr] = w2; Ws[lk + 3][lr] = w3;
        __syncthreads();
#pragma unroll
        for (int kk = 0; kk < 16; ++kk) {
            float4 av = *(const float4*)(&As[kk][ty << 2]);
            float4 wv = *(const float4*)(&Ws[kk][tx << 2]);
            float aa[4] = { av.x, av.y, av.z, av.w };
            float ww[4] = { wv.x, wv.y, wv.z, wv.w };
#pragma unroll
            for (int i = 0; i < 4; ++i)
#pragma unroll
                for (int j = 0; j < 4; ++j)
                    acc[i][j] = fmaf(aa[i], ww[j], acc[i][j]);
        }
    }

#pragma unroll
    for (int i = 0; i < 4; ++i) {
        const int row = m0 + (ty << 2) + i;
        if (row >= M) continue;
#pragma unroll
        for (int j = 0; j < 4; ++j) {
            const int col = n0 + (tx << 2) + j;
            if (col >= N) continue;
            float t = acc[i][j];
            if (bias) t += bias[col];
            if (act == 1) t = tanhfast(t);
            C[(size_t)row * N + col] = t;
        }
    }
}

// ---------------------------------------------------------------------------
// WT[200][600] = W[600][200]^T
// ---------------------------------------------------------------------------
__global__ __launch_bounds__(256)
void transpose_w(const float* __restrict__ W, float* __restrict__ WT)
{
    int id = blockIdx.x * 256 + threadIdx.x;
    if (id < 120000) {
        int e = id / 600, j = id - e * 600;
        WT[id] = W[(size_t)j * 200 + e];
    }
}

// ---------------------------------------------------------------------------
// re[i] = emb[resp[i]] rows, float4-wide
// ---------------------------------------------------------------------------
__global__ __launch_bounds__(256)
void gather_re_k(const int* __restrict__ resp, const float* __restrict__ emb,
                 float* __restrict__ re)
{
    int i = blockIdx.x * 256 + threadIdx.x;   // one float4 each
    if (i < 25600 * 50) {
        int row = i / 50, e4 = i - row * 50;
        ((float4*)re)[(size_t)row * 50 + e4] =
            ((const float4*)emb)[(size_t)resp[row] * 50 + e4];
    }
}

// ---------------------------------------------------------------------------
// One GRU time step, fused gh-GEMM + gates. Two groups per launch.
// h rows have stride 200 (dense ping-pong buffers). Optional archives.
// ---------------------------------------------------------------------------
struct GruArgs {
    const float* hprev;        // stride 200; null => h=0
    const float* xp;           // + r*xps
    const float* WT;           // [200][600] transposed Whh
    const float* bhh;
    float* hout;               // stride 200
    float* arch32;             // optional, + r*10000 (pre-offset by t*200)
    __hip_bfloat16* arch16;    // optional, + r*10000 (pre-offset by t*200)
    int M, xps;
};

__global__ __launch_bounds__(256)
void gru_step(GruArgs ga, GruArgs gb, int nblk0)
{
    const bool grp0 = (int)blockIdx.x < nblk0;
    GruArgs g = grp0 ? ga : gb;
    const int brow = grp0 ? blockIdx.x : (blockIdx.x - nblk0);

    __shared__ float h[20][200];
    const int tid = threadIdx.x;
    if (g.hprev) {
        for (int idx = tid; idx < 4000; idx += 256) {
            int rr = idx / 200, e = idx - rr * 200;
            int r = brow * 20 + rr;
            h[rr][e] = (r < g.M) ? g.hprev[(size_t)r * 200 + e] : 0.0f;
        }
    } else {
        for (int idx = tid; idx < 4000; idx += 256) ((float*)h)[idx] = 0.0f;
    }
    __syncthreads();
    if (tid >= 250) return;

    const int rg = tid / 50;            // 0..4  (4-row group)
    const int jg = tid - rg * 50;       // 0..49
    const int j0 = jg * 4;

    float ar[4][4] = {}, az[4][4] = {}, an[4][4] = {};
    if (g.hprev) {
        const float* wt = g.WT;
#pragma unroll 4
        for (int e = 0; e < 200; ++e) {
            float4 wr = *(const float4*)(wt + (size_t)e * 600 + j0);
            float4 wz = *(const float4*)(wt + (size_t)e * 600 + 200 + j0);
            float4 wn = *(const float4*)(wt + (size_t)e * 600 + 400 + j0);
#pragma unroll
            for (int i = 0; i < 4; ++i) {
                float hv = h[rg * 4 + i][e];
                ar[i][0] = fmaf(hv, wr.x, ar[i][0]); ar[i][1] = fmaf(hv, wr.y, ar[i][1]);
                ar[i][2] = fmaf(hv, wr.z, ar[i][2]); ar[i][3] = fmaf(hv, wr.w, ar[i][3]);
                az[i][0] = fmaf(hv, wz.x, az[i][0]); az[i][1] = fmaf(hv, wz.y, az[i][1]);
                az[i][2] = fmaf(hv, wz.z, az[i][2]); az[i][3] = fmaf(hv, wz.w, az[i][3]);
                an[i][0] = fmaf(hv, wn.x, an[i][0]); an[i][1] = fmaf(hv, wn.y, an[i][1]);
                an[i][2] = fmaf(hv, wn.z, an[i][2]); an[i][3] = fmaf(hv, wn.w, an[i][3]);
            }
        }
    }
#pragma unroll
    for (int i = 0; i < 4; ++i) {
        const int r = brow * 20 + rg * 4 + i;
        if (r >= g.M) continue;
        const float* xpr = g.xp + (size_t)r * g.xps;
        float* ho = g.hout + (size_t)r * 200;
#pragma unroll
        for (int j = 0; j < 4; ++j) {
            const int c = j0 + j;
            const float ghr = ar[i][j] + g.bhh[c];
            const float ghz = az[i][j] + g.bhh[200 + c];
            const float ghn = an[i][j] + g.bhh[400 + c];
            const float rr = sigm(xpr[c] + ghr);
            const float zz = sigm(xpr[200 + c] + ghz);
            const float nn = tanhfast(xpr[400 + c] + rr * ghn);
            const float hn = (1.0f - zz) * nn + zz * h[rg * 4 + i][c];
            ho[c] = hn;
            if (g.arch32) g.arch32[(size_t)r * 10000 + c] = hn;
            if (g.arch16) g.arch16[(size_t)r * 10000 + c] = __float2bfloat16(hn);
        }
    }
}

// ---------------------------------------------------------------------------
// Fused per-(b,u): m1 = emb[utt] @ re^T, m2 = ug16 @ rgA^T (both 50x50,K=200)
// then conv3x3(2->8)+bias+relu+maxpool3x3 s3 -> pooled[bu, 8*16*16]
// ---------------------------------------------------------------------------
__global__ __launch_bounds__(256)
void match_conv_pool(const int* __restrict__ utt, const float* __restrict__ emb,
                     const __hip_bfloat16* __restrict__ ug16,
                     const float* __restrict__ re, const float* __restrict__ rgA,
                     const float* __restrict__ cw, const float* __restrict__ cb,
                     float* __restrict__ pooled)
{
    const int bu = blockIdx.x;        // 0..5119
    const int b = bu / 10;
    __shared__ float Bs[50][201];     // 40.2 KB
    __shared__ float m[2][50][50];    // 20 KB
    __shared__ float w[144];
    __shared__ float bsh[8];
    const int tid = threadIdx.x;
    if (tid < 144) w[tid] = cw[tid];
    if (tid >= 144 && tid < 152) bsh[tid - 144] = cb[tid - 144];

    // ---- stage re[b] ----
    for (int idx = tid; idx < 10000; idx += 256) {
        int t = idx / 200, e = idx - t * 200;
        Bs[t][e] = re[(size_t)b * 10000 + idx];
    }
    __syncthreads();
    // ---- m1 ----
    for (int task = tid; task < 625; task += 256) {
        int lq = task / 25, tq = task - lq * 25;
        const float* a0 = emb + (size_t)utt[bu * 50 + lq] * 200;
        const float* a1 = emb + (size_t)utt[bu * 50 + lq + 25] * 200;
        float s00 = 0, s01 = 0, s10 = 0, s11 = 0;
#pragma unroll 4
        for (int e = 0; e < 200; ++e) {
            float av0 = a0[e], av1 = a1[e];
            float bv0 = Bs[tq][e], bv1 = Bs[tq + 25][e];
            s00 = fmaf(av0, bv0, s00); s01 = fmaf(av0, bv1, s01);
            s10 = fmaf(av1, bv0, s10); s11 = fmaf(av1, bv1, s11);
        }
        m[0][lq][tq] = s00;           m[0][lq][tq + 25] = s01;
        m[0][lq + 25][tq] = s10;      m[0][lq + 25][tq + 25] = s11;
    }
    __syncthreads();
    // ---- stage rgA[b] ----
    for (int idx = tid; idx < 10000; idx += 256) {
        int t = idx / 200, e = idx - t * 200;
        Bs[t][e] = rgA[(size_t)b * 10000 + idx];
    }
    __syncthreads();
    // ---- m2 ----
    for (int task = tid; task < 625; task += 256) {
        int lq = task / 25, tq = task - lq * 25;
        const __hip_bfloat16* a0 = ug16 + (size_t)bu * 10000 + (size_t)lq * 200;
        const __hip_bfloat16* a1 = a0 + 25 * 200;
        float s00 = 0, s01 = 0, s10 = 0, s11 = 0;
#pragma unroll 4
        for (int e = 0; e < 200; ++e) {
            float av0 = __bfloat162float(a0[e]), av1 = __bfloat162float(a1[e]);
            float bv0 = Bs[tq][e], bv1 = Bs[tq + 25][e];
            s00 = fmaf(av0, bv0, s00); s01 = fmaf(av0, bv1, s01);
            s10 = fmaf(av1, bv0, s10); s11 = fmaf(av1, bv1, s11);
        }
        m[1][lq][tq] = s00;           m[1][lq][tq + 25] = s01;
        m[1][lq + 25][tq] = s10;      m[1][lq + 25][tq + 25] = s11;
    }
    __syncthreads();
    // ---- conv + relu + maxpool ----
#pragma unroll
    for (int k = 0; k < 8; ++k) {
        const int o = tid + k * 256;            // 0..2047
        const int c = o >> 8, ph = (o >> 4) & 15, pw = o & 15;
        float mx = -1e30f;
#pragma unroll
        for (int p = 0; p < 3; ++p)
#pragma unroll
            for (int q = 0; q < 3; ++q) {
                const int y = ph * 3 + p, x = pw * 3 + q;
                float s = bsh[c];
#pragma unroll
                for (int ci = 0; ci < 2; ++ci)
#pragma unroll
                    for (int dy = 0; dy < 3; ++dy)
#pragma unroll
                        for (int dx = 0; dx < 3; ++dx)
                            s = fmaf(w[(c * 2 + ci) * 9 + dy * 3 + dx],
                                     m[ci][y + dy][x + dx], s);
                s = fmaxf(s, 0.0f);
                mx = fmaxf(mx, s);
            }
        pooled[(size_t)bu * 2048 + o] = mx;
    }
}

// ---------------------------------------------------------------------------
__global__ __launch_bounds__(256)
void final_logit(const float* __restrict__ hf, const float* __restrict__ fw,
                 const float* __restrict__ fb, float* __restrict__ out)
{
    int b = blockIdx.x * 256 + threadIdx.x;
    if (b < 512) {
        float s = fb[0];
        for (int k = 0; k < 200; ++k) s = fmaf(hf[(size_t)b * 200 + k], fw[k], s);
        out[b] = sigm(s);
    }
}

__global__ __launch_bounds__(256)
void fill_out(float* __restrict__ out)
{
    int i = blockIdx.x * 256 + threadIdx.x;
    if (i < 512) out[i] = 0.0f;
}

// ---------------------------------------------------------------------------
extern "C" void kernel_launch(void* const* d_in, const int* in_sizes, int n_in,
                              void* d_out, int out_size, void* d_ws, size_t ws_size,
                              hipStream_t stream)
{
    const int*   utt    = (const int*)d_in[0];
    const int*   resp   = (const int*)d_in[1];
    const float* emb    = (const float*)d_in[2];
    const float* W_ih_u = (const float*)d_in[3];
    const float* W_hh_u = (const float*)d_in[4];
    const float* b_ih_u = (const float*)d_in[5];
    const float* b_hh_u = (const float*)d_in[6];
    const float* W_ih_r = (const float*)d_in[7];
    const float* W_hh_r = (const float*)d_in[8];
    const float* b_ih_r = (const float*)d_in[9];
    const float* b_hh_r = (const float*)d_in[10];
    const float* conv_w = (const float*)d_in[11];
    const float* conv_b = (const float*)d_in[12];
    const float* lin_w  = (const float*)d_in[13];
    const float* lin_b  = (const float*)d_in[14];
    const float* Amat   = (const float*)d_in[15];
    const float* W_ih_f = (const float*)d_in[16];
    const float* W_hh_f = (const float*)d_in[17];
    const float* b_ih_f = (const float*)d_in[18];
    const float* b_hh_f = (const float*)d_in[19];
    const float* flin_w = (const float*)d_in[20];
    const float* flin_b = (const float*)d_in[21];
    float* out = (float*)d_out;
    float* ws  = (float*)d_ws;

    size_t off = 0;
    auto alloc = [&](size_t n) { float* p = ws + off; off += (n + 63) & ~((size_t)63); return p; };
    float* WT_u  = alloc(120000);
    float* WT_r  = alloc(120000);
    float* WT_f  = alloc(120000);
    float* re    = alloc(5120000);     // [512,50,200] f32
    float* rg    = alloc(5120000);     // [512,50,200] f32 archive
    float* xpr   = alloc(15360000);    // [25600,600] f32; post-scan: pooled/mv/xpf/hf
    float* hpp   = alloc(2252800);     // 2 x [5632,200] f32 ping-pong
    float* ug16f = alloc(25600000);    // [5120,50,200] bf16 archive (slots as floats)
    float* xpu   = alloc(3072000);     // [5120,600] f32 per-step input proj
    float* rgA   = alloc(5120000);     // [25600,200] f32

    // guard: workspace too small -> clean failure instead of device fault
    if (off * sizeof(float) > ws_size) {
        hipLaunchKernelGGL(fill_out, dim3(2), dim3(256), 0, stream, out);
        return;
    }

    __hip_bfloat16* ug16 = (__hip_bfloat16*)ug16f;
    float* hpp0 = hpp;
    float* hpp1 = hpp + 1126400;
    // post-scan aliases inside xpr (dead after the scan)
    float* pooled = xpr;               // [5120,2048] = 10,485,760
    float* mv     = xpr + 10600000;    // [5120,50]
    float* xpf    = xpr + 11000000;    // [5120,600]
    float* hfA    = xpr + 14200000;    // [512,200]
    float* hfB    = xpr + 14350000;    // [512,200]

    // 1. transpose recurrent weights
    hipLaunchKernelGGL(transpose_w, dim3(469), dim3(256), 0, stream, W_hh_u, WT_u);
    hipLaunchKernelGGL(transpose_w, dim3(469), dim3(256), 0, stream, W_hh_r, WT_r);
    hipLaunchKernelGGL(transpose_w, dim3(469), dim3(256), 0, stream, W_hh_f, WT_f);
    // 2. gather response embeddings
    hipLaunchKernelGGL(gather_re_k, dim3(5000), dim3(256), 0, stream, resp, emb, re);
    // 3. xproj_r = re @ W_ih_r^T + b_ih_r   (rows gathered from emb directly)
    hipLaunchKernelGGL(gemm_tn, dim3(400, 10), dim3(256), 0, stream,
                       emb, resp, 1, 0, W_ih_r, b_ih_r, xpr, 25600, 600, 200, 0);
    // 4. merged utterance+response GRU scan (50 steps, per-step input proj)
    for (int t = 0; t < 50; ++t) {
        // xpu = emb[utt[:, t]] @ W_ih_u^T + b_ih_u   [5120,600]
        hipLaunchKernelGGL(gemm_tn, dim3(80, 10), dim3(256), 0, stream,
                           emb, utt, 50, t, W_ih_u, b_ih_u, xpu, 5120, 600, 200, 0);
        float* hsrc = (t & 1) ? hpp0 : hpp1;
        float* hdst = (t & 1) ? hpp1 : hpp0;
        GruArgs ga, gb;
        ga.hprev = t ? hsrc : nullptr;
        ga.xp = xpu; ga.xps = 600;
        ga.WT = WT_u; ga.bhh = b_hh_u;
        ga.hout = hdst; ga.arch32 = nullptr; ga.arch16 = ug16 + (size_t)t * 200;
        ga.M = 5120;
        gb.hprev = t ? (hsrc + 1024000) : nullptr;
        gb.xp = xpr + (size_t)t * 600; gb.xps = 30000;
        gb.WT = WT_r; gb.bhh = b_hh_r;
        gb.hout = hdst + 1024000; gb.arch32 = rg + (size_t)t * 200; gb.arch16 = nullptr;
        gb.M = 512;
        hipLaunchKernelGGL(gru_step, dim3(282), dim3(256), 0, stream, ga, gb, 256);
    }
    // 5. rgA = rg @ Amat^T
    hipLaunchKernelGGL(gemm_tn, dim3(400, 4), dim3(256), 0, stream,
                       rg, (const int*)nullptr, 1, 0, Amat, (const float*)nullptr,
                       rgA, 25600, 200, 200, 0);
    // 6. fused match(m1,m2) + conv + relu + maxpool
    hipLaunchKernelGGL(match_conv_pool, dim3(5120), dim3(256), 0, stream,
                       utt, emb, ug16, re, rgA, conv_w, conv_b, pooled);
    // 7. mv = tanh(pooled @ lin_w^T + lin_b)
    hipLaunchKernelGGL(gemm_tn, dim3(80, 1), dim3(256), 0, stream,
                       pooled, (const int*)nullptr, 1, 0, lin_w, lin_b, mv,
                       5120, 50, 2048, 1);
    // 8. xproj_f = mv @ W_ih_f^T + b_ih_f
    hipLaunchKernelGGL(gemm_tn, dim3(80, 10), dim3(256), 0, stream,
                       mv, (const int*)nullptr, 1, 0, W_ih_f, b_ih_f, xpf,
                       5120, 600, 50, 0);
    // 9. final GRU over U=10 steps (M=512)
    for (int t = 0; t < 10; ++t) {
        GruArgs ga;
        ga.hprev = t ? ((t & 1) ? hfA : hfB) : nullptr;
        ga.xp = xpf + (size_t)t * 600; ga.xps = 6000;
        ga.WT = WT_f; ga.bhh = b_hh_f;
        ga.hout = (t & 1) ? hfB : hfA;
        ga.arch32 = nullptr; ga.arch16 = nullptr;
        ga.M = 512;
        hipLaunchKernelGGL(gru_step, dim3(26), dim3(256), 0, stream, ga, ga, 26);
    }
    // 10. logits + sigmoid  (h_last = hfB after t=9)
    hipLaunchKernelGGL(final_logit, dim3(2), dim3(256), 0, stream, hfB, flin_w, flin_b, out);
}

// Round 5
// 3982.205 us; speedup vs baseline: 2.1115x; 2.1115x over previous
//
#include <hip/hip_runtime.h>
#include <hip/hip_bf16.h>

// ---------------------------------------------------------------------------
// SMN forward. B=512 U=10 L=50 E=200 H=200 V=50000
// ---------------------------------------------------------------------------

__device__ __forceinline__ float sigm(float x) { return 1.0f / (1.0f + __expf(-x)); }
__device__ __forceinline__ float tanhfast(float x) {
    float e = __expf(2.0f * x);
    return 1.0f - 2.0f / (e + 1.0f);
}
__device__ __forceinline__ float bl(unsigned x) { return __uint_as_float(x << 16); }
__device__ __forceinline__ float bh(unsigned x) { return __uint_as_float(x & 0xffff0000u); }
__device__ __forceinline__ unsigned packbf(float a, float b) {
    union { __hip_bfloat16 h[2]; unsigned u; } cv;
    cv.h[0] = __float2bfloat16(a); cv.h[1] = __float2bfloat16(b);
    return cv.u;
}

// ---------------------------------------------------------------------------
// C[M,N] = act(A[M,K] @ W[N,K]^T + bias).  A f32 or bf16, C f32 or bf16.
// Optional row gather: row m uses A + gidx[m*gstride+goff]*K.
// ---------------------------------------------------------------------------
__global__ __launch_bounds__(256)
void gemm_tn(const void* __restrict__ Av, int a_bf16,
             const int* __restrict__ gidx, int gstride, int goff,
             const float* __restrict__ W, const float* __restrict__ bias,
             void* __restrict__ Cv, int c_bf16,
             int M, int N, int K, int act)
{
    __shared__ float As[16][64];
    __shared__ float Ws[16][64];
    const int tid = threadIdx.x;
    const int m0 = blockIdx.x * 64;
    const int n0 = blockIdx.y * 64;
    const int lr = tid >> 2;
    const int lk = (tid & 3) << 2;
    const int tx = tid & 15, ty = tid >> 4;

    float acc[4][4];
#pragma unroll
    for (int i = 0; i < 4; ++i)
#pragma unroll
        for (int j = 0; j < 4; ++j) acc[i][j] = 0.0f;

    const int am = m0 + lr;
    size_t arow_off = 0; bool avalid = (am < M);
    if (avalid) arow_off = (size_t)(gidx ? gidx[(size_t)am * gstride + goff] : am) * K;
    const float* arow32 = (const float*)Av + arow_off;
    const __hip_bfloat16* arow16 = (const __hip_bfloat16*)Av + arow_off;
    const int wn = n0 + lr;
    const float* wrow = (wn < N) ? (W + (size_t)wn * K) : nullptr;

    for (int kb = 0; kb < K; kb += 16) {
        const int k = kb + lk;
        float a0 = 0, a1 = 0, a2 = 0, a3 = 0, w0 = 0, w1 = 0, w2 = 0, w3 = 0;
        if (avalid) {
            if (a_bf16) {
                if (k + 3 < K) {
                    uint2 p = *(const uint2*)(arow16 + k);
                    a0 = bl(p.x); a1 = bh(p.x); a2 = bl(p.y); a3 = bh(p.y);
                } else {
                    if (k < K) a0 = __bfloat162float(arow16[k]);
                    if (k + 1 < K) a1 = __bfloat162float(arow16[k + 1]);
                    if (k + 2 < K) a2 = __bfloat162float(arow16[k + 2]);
                }
            } else {
                if (k + 3 < K) { float4 v = *(const float4*)(arow32 + k); a0 = v.x; a1 = v.y; a2 = v.z; a3 = v.w; }
                else { if (k < K) a0 = arow32[k]; if (k + 1 < K) a1 = arow32[k + 1]; if (k + 2 < K) a2 = arow32[k + 2]; }
            }
        }
        if (wrow) {
            if (k + 3 < K) { float4 v = *(const float4*)(wrow + k); w0 = v.x; w1 = v.y; w2 = v.z; w3 = v.w; }
            else { if (k < K) w0 = wrow[k]; if (k + 1 < K) w1 = wrow[k + 1]; if (k + 2 < K) w2 = wrow[k + 2]; }
        }
        __syncthreads();
        As[lk + 0][lr] = a0; As[lk + 1][lr] = a1; As[lk + 2][lr] = a2; As[lk + 3][lr] = a3;
        Ws[lk + 0][lr] = w0; Ws[lk + 1][lr] = w1; Ws[lk + 2][lr] = w2; Ws[lk + 3][lr] = w3;
        __syncthreads();
#pragma unroll
        for (int kk = 0; kk < 16; ++kk) {
            float4 av = *(const float4*)(&As[kk][ty << 2]);
            float4 wv = *(const float4*)(&Ws[kk][tx << 2]);
            float aa[4] = { av.x, av.y, av.z, av.w };
            float ww[4] = { wv.x, wv.y, wv.z, wv.w };
#pragma unroll
            for (int i = 0; i < 4; ++i)
#pragma unroll
                for (int j = 0; j < 4; ++j)
                    acc[i][j] = fmaf(aa[i], ww[j], acc[i][j]);
        }
    }

#pragma unroll
    for (int i = 0; i < 4; ++i) {
        const int row = m0 + (ty << 2) + i;
        if (row >= M) continue;
#pragma unroll
        for (int j = 0; j < 4; ++j) {
            const int col = n0 + (tx << 2) + j;
            if (col >= N) continue;
            float t = acc[i][j];
            if (bias) t += bias[col];
            if (act == 1) t = tanhfast(t);
            if (c_bf16) ((__hip_bfloat16*)Cv)[(size_t)row * N + col] = __float2bfloat16(t);
            else        ((float*)Cv)[(size_t)row * N + col] = t;
        }
    }
}

// ---------------------------------------------------------------------------
// Three [600,200] -> [200,600] transposes in one launch
// ---------------------------------------------------------------------------
__global__ __launch_bounds__(256)
void transpose3(const float* __restrict__ Wu, const float* __restrict__ Wr,
                const float* __restrict__ Wf, float* __restrict__ Tu,
                float* __restrict__ Tr, float* __restrict__ Tf)
{
    int id = blockIdx.x * 256 + threadIdx.x;
    if (id >= 360000) return;
    int tab = id / 120000, r = id - tab * 120000;
    int e = r / 600, j = r - e * 600;
    const float* src = tab == 0 ? Wu : (tab == 1 ? Wr : Wf);
    float* dst = tab == 0 ? Tu : (tab == 1 ? Tr : Tf);
    dst[r] = src[(size_t)j * 200 + e];
}

// ---------------------------------------------------------------------------
// re16[row] = bf16(emb[resp[row]])
// ---------------------------------------------------------------------------
__global__ __launch_bounds__(256)
void gather_re16(const int* __restrict__ resp, const float* __restrict__ emb,
                 __hip_bfloat16* __restrict__ re16)
{
    int idx = blockIdx.x * 256 + threadIdx.x;    // one bf16-pair each
    if (idx < 2560000) {
        int row = idx / 100, q = idx - row * 100;
        float2 v = *(const float2*)(emb + (size_t)resp[row] * 200 + 2 * q);
        ((unsigned*)re16)[idx] = packbf(v.x, v.y);
    }
}

// ---------------------------------------------------------------------------
// Persistent dual-GRU scan: 256 blocks x 512 thr, 50 steps internal.
// Block owns 20 utterance rows + 2 response rows; h lives in LDS.
// utt x-proj gathered from EPu table (bf16, bias folded); resp from xpr16.
// ---------------------------------------------------------------------------
__global__ __launch_bounds__(512)
void scan_gru(const int* __restrict__ utt,
              const __hip_bfloat16* __restrict__ EPu,
              const __hip_bfloat16* __restrict__ xpr16,
              const float* __restrict__ WTu, const float* __restrict__ WTr,
              const float* __restrict__ bhu, const float* __restrict__ bhr,
              __hip_bfloat16* __restrict__ ug16,
              __hip_bfloat16* __restrict__ rg16)
{
    const int blk = blockIdx.x;          // 0..255
    const int tid = threadIdx.x;
    const int u0 = blk * 20;
    const int r0 = blk * 2;

    __shared__ float h[22][201];                       // rows 0..19 utt, 20..21 resp
    __shared__ __align__(16) __hip_bfloat16 xpu[20][600];
    __shared__ float xpr_s[2][600];

    for (int i = tid; i < 22 * 201; i += 512) ((float*)h)[i] = 0.0f;
    __syncthreads();

    const int rg = tid / 50;             // 0..9 for tid<500
    const int jg = tid % 50;
    const int j0 = 4 * jg;
    const int brr = tid / 100;           // 0..1 for tid<200
    const int bj0 = 2 * (tid % 100);

    for (int t = 0; t < 50; ++t) {
        // ---- stage x-projections ----
        for (int idx = tid; idx < 1500; idx += 512) {        // 20 rows x 75 uint4
            int row = idx / 75, q = idx - row * 75;
            int tok = utt[(u0 + row) * 50 + t];
            ((uint4*)&xpu[row][0])[q] = ((const uint4*)(EPu + (size_t)tok * 600))[q];
        }
        for (int idx = tid; idx < 600; idx += 512) {         // 2 rows x 300 uint
            int row = idx / 300, q = idx - row * 300;
            unsigned p = ((const unsigned*)(xpr16 + (size_t)((r0 + row) * 50 + t) * 600))[q];
            xpr_s[row][2 * q] = bl(p);
            xpr_s[row][2 * q + 1] = bh(p);
        }
        // ---- gh accumulation (reads h) ----
        float aR[2][4] = {}, aZ[2][4] = {}, aN[2][4] = {};
        if (tid < 500) {
            const int ra = 2 * rg, rb = 2 * rg + 1;
#pragma unroll 2
            for (int e = 0; e < 200; ++e) {
                const float* w = WTu + (size_t)e * 600;
                float4 wr = *(const float4*)(w + j0);
                float4 wz = *(const float4*)(w + 200 + j0);
                float4 wn = *(const float4*)(w + 400 + j0);
                float h0 = h[ra][e], h1 = h[rb][e];
                aR[0][0] = fmaf(h0, wr.x, aR[0][0]); aR[0][1] = fmaf(h0, wr.y, aR[0][1]);
                aR[0][2] = fmaf(h0, wr.z, aR[0][2]); aR[0][3] = fmaf(h0, wr.w, aR[0][3]);
                aZ[0][0] = fmaf(h0, wz.x, aZ[0][0]); aZ[0][1] = fmaf(h0, wz.y, aZ[0][1]);
                aZ[0][2] = fmaf(h0, wz.z, aZ[0][2]); aZ[0][3] = fmaf(h0, wz.w, aZ[0][3]);
                aN[0][0] = fmaf(h0, wn.x, aN[0][0]); aN[0][1] = fmaf(h0, wn.y, aN[0][1]);
                aN[0][2] = fmaf(h0, wn.z, aN[0][2]); aN[0][3] = fmaf(h0, wn.w, aN[0][3]);
                aR[1][0] = fmaf(h1, wr.x, aR[1][0]); aR[1][1] = fmaf(h1, wr.y, aR[1][1]);
                aR[1][2] = fmaf(h1, wr.z, aR[1][2]); aR[1][3] = fmaf(h1, wr.w, aR[1][3]);
                aZ[1][0] = fmaf(h1, wz.x, aZ[1][0]); aZ[1][1] = fmaf(h1, wz.y, aZ[1][1]);
                aZ[1][2] = fmaf(h1, wz.z, aZ[1][2]); aZ[1][3] = fmaf(h1, wz.w, aZ[1][3]);
                aN[1][0] = fmaf(h1, wn.x, aN[1][0]); aN[1][1] = fmaf(h1, wn.y, aN[1][1]);
                aN[1][2] = fmaf(h1, wn.z, aN[1][2]); aN[1][3] = fmaf(h1, wn.w, aN[1][3]);
            }
        }
        float bR[2] = {}, bZ[2] = {}, bN[2] = {};
        if (tid < 200) {
#pragma unroll 2
            for (int e = 0; e < 200; ++e) {
                const float* w = WTr + (size_t)e * 600;
                float2 wr = *(const float2*)(w + bj0);
                float2 wz = *(const float2*)(w + 200 + bj0);
                float2 wn = *(const float2*)(w + 400 + bj0);
                float hv = h[20 + brr][e];
                bR[0] = fmaf(hv, wr.x, bR[0]); bR[1] = fmaf(hv, wr.y, bR[1]);
                bZ[0] = fmaf(hv, wz.x, bZ[0]); bZ[1] = fmaf(hv, wz.y, bZ[1]);
                bN[0] = fmaf(hv, wn.x, bN[0]); bN[1] = fmaf(hv, wn.y, bN[1]);
            }
        }
        __syncthreads();
        // ---- epilogue: gates, h update, archives ----
        if (tid < 500) {
#pragma unroll
            for (int i = 0; i < 2; ++i) {
                const int row = 2 * rg + i;
                float hn4[4];
#pragma unroll
                for (int j = 0; j < 4; ++j) {
                    const int c = j0 + j;
                    float xr = __bfloat162float(xpu[row][c]);
                    float xz = __bfloat162float(xpu[row][200 + c]);
                    float xn = __bfloat162float(xpu[row][400 + c]);
                    float rr = sigm(xr + aR[i][j] + bhu[c]);
                    float zz = sigm(xz + aZ[i][j] + bhu[200 + c]);
                    float nn = tanhfast(xn + rr * (aN[i][j] + bhu[400 + c]));
                    hn4[j] = (1.0f - zz) * nn + zz * h[row][c];
                }
#pragma unroll
                for (int j = 0; j < 4; ++j) h[row][j0 + j] = hn4[j];
                uint2 pk;
                pk.x = packbf(hn4[0], hn4[1]);
                pk.y = packbf(hn4[2], hn4[3]);
                *(uint2*)(ug16 + ((size_t)(u0 + row) * 50 + t) * 200 + j0) = pk;
            }
        }
        if (tid < 200) {
            const int row = 20 + brr;
            const int grow = r0 + brr;
#pragma unroll
            for (int j = 0; j < 2; ++j) {
                const int c = bj0 + j;
                float xr = xpr_s[brr][c];
                float xz = xpr_s[brr][200 + c];
                float xn = xpr_s[brr][400 + c];
                float rr = sigm(xr + bR[j] + bhr[c]);
                float zz = sigm(xz + bZ[j] + bhr[200 + c]);
                float nn = tanhfast(xn + rr * (bN[j] + bhr[400 + c]));
                float hn = (1.0f - zz) * nn + zz * h[row][c];
                h[row][c] = hn;
                rg16[((size_t)grow * 50 + t) * 200 + c] = __float2bfloat16(hn);
            }
        }
        __syncthreads();
    }
}

// ---------------------------------------------------------------------------
// Fused m1/m2 match + conv3x3(2->8)+relu+maxpool3x3 per (b,u).
// All GEMM operands staged in LDS as bf16.
// ---------------------------------------------------------------------------
__global__ __launch_bounds__(256)
void match_conv_pool(const int* __restrict__ utt, const float* __restrict__ emb,
                     const __hip_bfloat16* __restrict__ ug16,
                     const __hip_bfloat16* __restrict__ re16,
                     const __hip_bfloat16* __restrict__ rgA16,
                     const float* __restrict__ cw, const float* __restrict__ cb,
                     float* __restrict__ pooled)
{
    const int bu = blockIdx.x, b = bu / 10;
    __shared__ __hip_bfloat16 As[50][204];
    __shared__ __hip_bfloat16 Bs[50][204];
    __shared__ float m[2][50][50];
    __shared__ float w[144];
    __shared__ float bsh[8];
    const int tid = threadIdx.x;
    if (tid < 144) w[tid] = cw[tid];
    if (tid >= 144 && tid < 152) bsh[tid - 144] = cb[tid - 144];

    // ---- stage m1 operands: As <- bf16(emb[utt rows]), Bs <- re16[b] ----
    for (int idx = tid; idx < 5000; idx += 256) {
        int l = idx / 100, q = idx - l * 100;
        int tok = utt[bu * 50 + l];
        float2 v = *(const float2*)(emb + (size_t)tok * 200 + 2 * q);
        *(unsigned*)&As[l][2 * q] = packbf(v.x, v.y);
        *(unsigned*)&Bs[l][2 * q] =
            ((const unsigned*)(re16 + (size_t)b * 10000 + (size_t)l * 200))[q];
    }
    __syncthreads();
#pragma unroll 1
    for (int ch = 0; ch < 2; ++ch) {
        for (int task = tid; task < 625; task += 256) {
            int lq = task / 25, tq = task - lq * 25;
            float s00 = 0, s01 = 0, s10 = 0, s11 = 0;
#pragma unroll 4
            for (int q = 0; q < 100; ++q) {
                unsigned a0 = *(const unsigned*)&As[lq][2 * q];
                unsigned a1 = *(const unsigned*)&As[lq + 25][2 * q];
                unsigned b0 = *(const unsigned*)&Bs[tq][2 * q];
                unsigned b1 = *(const unsigned*)&Bs[tq + 25][2 * q];
                float a0l = bl(a0), a0h = bh(a0), a1l = bl(a1), a1h = bh(a1);
                float b0l = bl(b0), b0h = bh(b0), b1l = bl(b1), b1h = bh(b1);
                s00 = fmaf(a0l, b0l, fmaf(a0h, b0h, s00));
                s01 = fmaf(a0l, b1l, fmaf(a0h, b1h, s01));
                s10 = fmaf(a1l, b0l, fmaf(a1h, b0h, s10));
                s11 = fmaf(a1l, b1l, fmaf(a1h, b1h, s11));
            }
            m[ch][lq][tq] = s00;           m[ch][lq][tq + 25] = s01;
            m[ch][lq + 25][tq] = s10;      m[ch][lq + 25][tq + 25] = s11;
        }
        __syncthreads();
        if (ch == 0) {
            // ---- restage for m2: As <- ug16[bu], Bs <- rgA16[b] ----
            for (int idx = tid; idx < 5000; idx += 256) {
                int l = idx / 100, q = idx - l * 100;
                *(unsigned*)&As[l][2 * q] =
                    ((const unsigned*)(ug16 + (size_t)bu * 10000 + (size_t)l * 200))[q];
                *(unsigned*)&Bs[l][2 * q] =
                    ((const unsigned*)(rgA16 + (size_t)b * 10000 + (size_t)l * 200))[q];
            }
            __syncthreads();
        }
    }
    // ---- conv + relu + maxpool ----
#pragma unroll
    for (int k = 0; k < 8; ++k) {
        const int o = tid + k * 256;
        const int c = o >> 8, ph = (o >> 4) & 15, pw = o & 15;
        float mx = -1e30f;
#pragma unroll
        for (int p = 0; p < 3; ++p)
#pragma unroll
            for (int q = 0; q < 3; ++q) {
                const int y = ph * 3 + p, x = pw * 3 + q;
                float s = bsh[c];
#pragma unroll
                for (int ci = 0; ci < 2; ++ci)
#pragma unroll
                    for (int dy = 0; dy < 3; ++dy)
#pragma unroll
                        for (int dx = 0; dx < 3; ++dx)
                            s = fmaf(w[(c * 2 + ci) * 9 + dy * 3 + dx],
                                     m[ci][y + dy][x + dx], s);
                s = fmaxf(s, 0.0f);
                mx = fmaxf(mx, s);
            }
        pooled[(size_t)bu * 2048 + o] = mx;
    }
}

// ---------------------------------------------------------------------------
// Persistent final GRU (10 steps) + logit + sigmoid. 256 blocks x 2 rows.
// ---------------------------------------------------------------------------
__global__ __launch_bounds__(256)
void final_gru(const float* __restrict__ xpf, const float* __restrict__ WTf,
               const float* __restrict__ bhf, const float* __restrict__ fw,
               const float* __restrict__ fb, float* __restrict__ out)
{
    const int blk = blockIdx.x;
    const int tid = threadIdx.x;
    __shared__ float h[2][201];
    for (int i = tid; i < 402; i += 256) ((float*)h)[i] = 0.0f;
    __syncthreads();
    const int rr = tid / 100;
    const int j0 = 2 * (tid % 100);
    for (int t = 0; t < 10; ++t) {
        float cR[2] = {}, cZ[2] = {}, cN[2] = {};
        if (tid < 200) {
#pragma unroll 2
            for (int e = 0; e < 200; ++e) {
                const float* w = WTf + (size_t)e * 600;
                float2 wr = *(const float2*)(w + j0);
                float2 wz = *(const float2*)(w + 200 + j0);
                float2 wn = *(const float2*)(w + 400 + j0);
                float hv = h[rr][e];
                cR[0] = fmaf(hv, wr.x, cR[0]); cR[1] = fmaf(hv, wr.y, cR[1]);
                cZ[0] = fmaf(hv, wz.x, cZ[0]); cZ[1] = fmaf(hv, wz.y, cZ[1]);
                cN[0] = fmaf(hv, wn.x, cN[0]); cN[1] = fmaf(hv, wn.y, cN[1]);
            }
        }
        __syncthreads();
        if (tid < 200) {
            const float* xp = xpf + ((size_t)(blk * 2 + rr) * 10 + t) * 600;
#pragma unroll
            for (int j = 0; j < 2; ++j) {
                const int c = j0 + j;
                float rrg = sigm(xp[c] + cR[j] + bhf[c]);
                float zz = sigm(xp[200 + c] + cZ[j] + bhf[200 + c]);
                float nn = tanhfast(xp[400 + c] + rrg * (cN[j] + bhf[400 + c]));
                h[rr][c] = (1.0f - zz) * nn + zz * h[rr][c];
            }
        }
        __syncthreads();
    }
    if (tid < 2) {
        float s = fb[0];
        for (int k = 0; k < 200; ++k) s = fmaf(h[tid][k], fw[k], s);
        out[blk * 2 + tid] = sigm(s);
    }
}

__global__ __launch_bounds__(256)
void fill_out(float* __restrict__ out)
{
    int i = blockIdx.x * 256 + threadIdx.x;
    if (i < 512) out[i] = 0.0f;
}

// ---------------------------------------------------------------------------
extern "C" void kernel_launch(void* const* d_in, const int* in_sizes, int n_in,
                              void* d_out, int out_size, void* d_ws, size_t ws_size,
                              hipStream_t stream)
{
    const int*   utt    = (const int*)d_in[0];
    const int*   resp   = (const int*)d_in[1];
    const float* emb    = (const float*)d_in[2];
    const float* W_ih_u = (const float*)d_in[3];
    const float* W_hh_u = (const float*)d_in[4];
    const float* b_ih_u = (const float*)d_in[5];
    const float* b_hh_u = (const float*)d_in[6];
    const float* W_ih_r = (const float*)d_in[7];
    const float* W_hh_r = (const float*)d_in[8];
    const float* b_ih_r = (const float*)d_in[9];
    const float* b_hh_r = (const float*)d_in[10];
    const float* conv_w = (const float*)d_in[11];
    const float* conv_b = (const float*)d_in[12];
    const float* lin_w  = (const float*)d_in[13];
    const float* lin_b  = (const float*)d_in[14];
    const float* Amat   = (const float*)d_in[15];
    const float* W_ih_f = (const float*)d_in[16];
    const float* W_hh_f = (const float*)d_in[17];
    const float* b_ih_f = (const float*)d_in[18];
    const float* b_hh_f = (const float*)d_in[19];
    const float* flin_w = (const float*)d_in[20];
    const float* flin_b = (const float*)d_in[21];
    float* out = (float*)d_out;
    float* ws  = (float*)d_ws;

    size_t off = 0;
    auto alloc = [&](size_t n) { float* p = ws + off; off += (n + 63) & ~((size_t)63); return p; };
    float* WT_u   = alloc(120000);
    float* WT_r   = alloc(120000);
    float* WT_f   = alloc(120000);
    float* re16f  = alloc(2560000);    // [25600,200] bf16 = 5.12M bf16 = 2.56M f32 slots
    float* EPuf   = alloc(15000000);   // [50000,600] bf16; post-scan: pooled
    float* xprf   = alloc(7680000);    // [25600,600] bf16; post-scan: mv/xpf
    float* ug16f  = alloc(25600000);   // [5120,50,200] bf16
    float* rg16f  = alloc(2560000);    // [512,50,200] bf16
    float* rgA16f = alloc(2560000);    // [25600,200] bf16 = 5.12M bf16 = 2.56M f32 slots
    // total 56.32M floats = 225 MB

    if (off * sizeof(float) > ws_size) {
        hipLaunchKernelGGL(fill_out, dim3(2), dim3(256), 0, stream, out);
        return;
    }

    __hip_bfloat16* re16  = (__hip_bfloat16*)re16f;
    __hip_bfloat16* EPu   = (__hip_bfloat16*)EPuf;
    __hip_bfloat16* xpr16 = (__hip_bfloat16*)xprf;
    __hip_bfloat16* ug16  = (__hip_bfloat16*)ug16f;
    __hip_bfloat16* rg16  = (__hip_bfloat16*)rg16f;
    __hip_bfloat16* rgA16 = (__hip_bfloat16*)rgA16f;
    float* pooled = EPuf;              // [5120,2048] f32 (EPu dead after scan)
    float* mv     = xprf;              // [5120,50] f32  (xpr dead after scan)
    float* xpf    = xprf + 400000;     // [5120,600] f32

    // 1. weight transposes
    hipLaunchKernelGGL(transpose3, dim3(1407), dim3(256), 0, stream,
                       W_hh_u, W_hh_r, W_hh_f, WT_u, WT_r, WT_f);
    // 2. response embedding gather (bf16)
    hipLaunchKernelGGL(gather_re16, dim3(10000), dim3(256), 0, stream, resp, emb, re16);
    // 3. EPu = bf16(emb @ W_ih_u^T + b_ih_u) for the whole vocab
    hipLaunchKernelGGL(gemm_tn, dim3(782, 10), dim3(256), 0, stream,
                       emb, 0, (const int*)nullptr, 1, 0, W_ih_u, b_ih_u,
                       EPu, 1, 50000, 600, 200, 0);
    // 4. xpr16 = bf16(emb[resp] @ W_ih_r^T + b_ih_r)
    hipLaunchKernelGGL(gemm_tn, dim3(400, 10), dim3(256), 0, stream,
                       emb, 0, resp, 1, 0, W_ih_r, b_ih_r,
                       xpr16, 1, 25600, 600, 200, 0);
    // 5. persistent dual-GRU scan (both GRUs, all 50 steps, one launch)
    hipLaunchKernelGGL(scan_gru, dim3(256), dim3(512), 0, stream,
                       utt, EPu, xpr16, WT_u, WT_r, b_hh_u, b_hh_r, ug16, rg16);
    // 6. rgA16 = bf16(rg @ Amat^T)
    hipLaunchKernelGGL(gemm_tn, dim3(400, 4), dim3(256), 0, stream,
                       rg16, 1, (const int*)nullptr, 1, 0, Amat, (const float*)nullptr,
                       rgA16, 1, 25600, 200, 200, 0);
    // 7. fused match + conv + pool
    hipLaunchKernelGGL(match_conv_pool, dim3(5120), dim3(256), 0, stream,
                       utt, emb, ug16, re16, rgA16, conv_w, conv_b, pooled);
    // 8. mv = tanh(pooled @ lin_w^T + lin_b)
    hipLaunchKernelGGL(gemm_tn, dim3(80, 1), dim3(256), 0, stream,
                       pooled, 0, (const int*)nullptr, 1, 0, lin_w, lin_b,
                       mv, 0, 5120, 50, 2048, 1);
    // 9. xpf = mv @ W_ih_f^T + b_ih_f
    hipLaunchKernelGGL(gemm_tn, dim3(80, 10), dim3(256), 0, stream,
                       mv, 0, (const int*)nullptr, 1, 0, W_ih_f, b_ih_f,
                       xpf, 0, 5120, 600, 50, 0);
    // 10. final GRU + logit + sigmoid
    hipLaunchKernelGGL(final_gru, dim3(256), dim3(256), 0, stream,
                       xpf, WT_f, b_hh_f, flin_w, flin_b, out);
}

// Round 6
// 3775.256 us; speedup vs baseline: 2.2273x; 1.0548x over previous
//
#include <hip/hip_runtime.h>
#include <hip/hip_bf16.h>

// ---------------------------------------------------------------------------
// SMN forward. B=512 U=10 L=50 E=200 H=200 V=50000
// ---------------------------------------------------------------------------

typedef __attribute__((ext_vector_type(8))) short short8v;   // 8 bf16 (4 VGPR)
typedef __attribute__((ext_vector_type(4))) float f32x4;

__device__ __forceinline__ float sigm(float x) { return 1.0f / (1.0f + __expf(-x)); }
__device__ __forceinline__ float tanhfast(float x) {
    float e = __expf(2.0f * x);
    return 1.0f - 2.0f / (e + 1.0f);
}
__device__ __forceinline__ float bl(unsigned x) { return __uint_as_float(x << 16); }
__device__ __forceinline__ float bh(unsigned x) { return __uint_as_float(x & 0xffff0000u); }
__device__ __forceinline__ unsigned packbf(float a, float b) {
    union { __hip_bfloat16 h[2]; unsigned u; } cv;
    cv.h[0] = __float2bfloat16(a); cv.h[1] = __float2bfloat16(b);
    return cv.u;
}

// ---------------------------------------------------------------------------
// MFMA GEMM: C16[M,N] = bf16(A[M,200] @ W[N,200]^T + bias)
// A f32 or bf16 (rows optionally gathered via gidx). K=200 padded to 232.
// Tile 64x64, 4 waves (2x2), each wave 2x2 fragments of 16x16, 7 K-steps.
// ---------------------------------------------------------------------------
__global__ __launch_bounds__(256)
void gemm_mfma(const void* __restrict__ Asrc, int a_bf16,
               const int* __restrict__ gidx,
               const float* __restrict__ W, const float* __restrict__ bias,
               __hip_bfloat16* __restrict__ C, int M, int N)
{
    __shared__ __hip_bfloat16 Al[64 * 232];   // 29.7 KB, row stride 464 B
    __shared__ __hip_bfloat16 Bl[64 * 232];
    const int tid = threadIdx.x;
    const int m0 = blockIdx.x * 64, n0 = blockIdx.y * 64;

    // stage A tile (convert to bf16, zero-pad K 200..231 and OOB rows)
    for (int idx = tid; idx < 64 * 29; idx += 256) {
        int r = idx / 29, q = idx - r * 29;
        int k0 = q * 8, row = m0 + r;
        uint4 val = make_uint4(0, 0, 0, 0);
        if (k0 < 200 && row < M) {
            size_t ar = (size_t)(gidx ? gidx[row] : row) * 200 + k0;
            if (a_bf16) {
                val = *(const uint4*)((const __hip_bfloat16*)Asrc + ar);
            } else {
                const float* ap = (const float*)Asrc + ar;
                float4 f0 = *(const float4*)ap;
                float4 f1 = *(const float4*)(ap + 4);
                val.x = packbf(f0.x, f0.y); val.y = packbf(f0.z, f0.w);
                val.z = packbf(f1.x, f1.y); val.w = packbf(f1.z, f1.w);
            }
        }
        *(uint4*)(Al + r * 232 + k0) = val;
    }
    // stage W tile (always f32 source)
    for (int idx = tid; idx < 64 * 29; idx += 256) {
        int r = idx / 29, q = idx - r * 29;
        int k0 = q * 8, row = n0 + r;
        uint4 val = make_uint4(0, 0, 0, 0);
        if (k0 < 200 && row < N) {
            const float* wp = W + (size_t)row * 200 + k0;
            float4 f0 = *(const float4*)wp;
            float4 f1 = *(const float4*)(wp + 4);
            val.x = packbf(f0.x, f0.y); val.y = packbf(f0.z, f0.w);
            val.z = packbf(f1.x, f1.y); val.w = packbf(f1.z, f1.w);
        }
        *(uint4*)(Bl + r * 232 + k0) = val;
    }
    __syncthreads();

    const int wid = tid >> 6, lane = tid & 63;
    const int wm = (wid >> 1) * 32, wn = (wid & 1) * 32;
    const int lrow = lane & 15, lk8 = (lane >> 4) * 8;
    f32x4 acc00 = {0.f, 0.f, 0.f, 0.f}, acc01 = {0.f, 0.f, 0.f, 0.f};
    f32x4 acc10 = {0.f, 0.f, 0.f, 0.f}, acc11 = {0.f, 0.f, 0.f, 0.f};
#pragma unroll
    for (int kk = 0; kk < 7; ++kk) {
        const int kb = kk * 32 + lk8;
        short8v a0 = *(const short8v*)(Al + (wm + lrow) * 232 + kb);
        short8v a1 = *(const short8v*)(Al + (wm + 16 + lrow) * 232 + kb);
        short8v b0 = *(const short8v*)(Bl + (wn + lrow) * 232 + kb);
        short8v b1 = *(const short8v*)(Bl + (wn + 16 + lrow) * 232 + kb);
        acc00 = __builtin_amdgcn_mfma_f32_16x16x32_bf16(a0, b0, acc00, 0, 0, 0);
        acc01 = __builtin_amdgcn_mfma_f32_16x16x32_bf16(a0, b1, acc01, 0, 0, 0);
        acc10 = __builtin_amdgcn_mfma_f32_16x16x32_bf16(a1, b0, acc10, 0, 0, 0);
        acc11 = __builtin_amdgcn_mfma_f32_16x16x32_bf16(a1, b1, acc11, 0, 0, 0);
    }
    // D mapping: col = lane&15, row = (lane>>4)*4 + r   [m89-verified]
    const int drow = (lane >> 4) * 4, dcol = lane & 15;
#pragma unroll
    for (int fm = 0; fm < 2; ++fm) {
#pragma unroll
        for (int fn = 0; fn < 2; ++fn) {
            const f32x4 av = (fm == 0) ? (fn == 0 ? acc00 : acc01)
                                       : (fn == 0 ? acc10 : acc11);
            const int gcol = n0 + wn + fn * 16 + dcol;
            if (gcol >= N) continue;
            const float bs = bias ? bias[gcol] : 0.0f;
#pragma unroll
            for (int r = 0; r < 4; ++r) {
                const int grow = m0 + wm + fm * 16 + drow + r;
                if (grow >= M) continue;
                C[(size_t)grow * N + gcol] = __float2bfloat16(av[r] + bs);
            }
        }
    }
}

// ---------------------------------------------------------------------------
// Generic fp32 GEMM (kept for small tails): C = act(A @ W^T + bias)
// ---------------------------------------------------------------------------
__global__ __launch_bounds__(256)
void gemm_tn(const void* __restrict__ Av, int a_bf16,
             const int* __restrict__ gidx, int gstride, int goff,
             const float* __restrict__ W, const float* __restrict__ bias,
             void* __restrict__ Cv, int c_bf16,
             int M, int N, int K, int act)
{
    __shared__ float As[16][64];
    __shared__ float Ws[16][64];
    const int tid = threadIdx.x;
    const int m0 = blockIdx.x * 64;
    const int n0 = blockIdx.y * 64;
    const int lr = tid >> 2;
    const int lk = (tid & 3) << 2;
    const int tx = tid & 15, ty = tid >> 4;

    float acc[4][4];
#pragma unroll
    for (int i = 0; i < 4; ++i)
#pragma unroll
        for (int j = 0; j < 4; ++j) acc[i][j] = 0.0f;

    const int am = m0 + lr;
    size_t arow_off = 0; bool avalid = (am < M);
    if (avalid) arow_off = (size_t)(gidx ? gidx[(size_t)am * gstride + goff] : am) * K;
    const float* arow32 = (const float*)Av + arow_off;
    const __hip_bfloat16* arow16 = (const __hip_bfloat16*)Av + arow_off;
    const int wn = n0 + lr;
    const float* wrow = (wn < N) ? (W + (size_t)wn * K) : nullptr;

    for (int kb = 0; kb < K; kb += 16) {
        const int k = kb + lk;
        float a0 = 0, a1 = 0, a2 = 0, a3 = 0, w0 = 0, w1 = 0, w2 = 0, w3 = 0;
        if (avalid) {
            if (a_bf16) {
                if (k + 3 < K) {
                    uint2 p = *(const uint2*)(arow16 + k);
                    a0 = bl(p.x); a1 = bh(p.x); a2 = bl(p.y); a3 = bh(p.y);
                } else {
                    if (k < K) a0 = __bfloat162float(arow16[k]);
                    if (k + 1 < K) a1 = __bfloat162float(arow16[k + 1]);
                    if (k + 2 < K) a2 = __bfloat162float(arow16[k + 2]);
                }
            } else {
                if (k + 3 < K) { float4 v = *(const float4*)(arow32 + k); a0 = v.x; a1 = v.y; a2 = v.z; a3 = v.w; }
                else { if (k < K) a0 = arow32[k]; if (k + 1 < K) a1 = arow32[k + 1]; if (k + 2 < K) a2 = arow32[k + 2]; }
            }
        }
        if (wrow) {
            if (k + 3 < K) { float4 v = *(const float4*)(wrow + k); w0 = v.x; w1 = v.y; w2 = v.z; w3 = v.w; }
            else { if (k < K) w0 = wrow[k]; if (k + 1 < K) w1 = wrow[k + 1]; if (k + 2 < K) w2 = wrow[k + 2]; }
        }
        __syncthreads();
        As[lk + 0][lr] = a0; As[lk + 1][lr] = a1; As[lk + 2][lr] = a2; As[lk + 3][lr] = a3;
        Ws[lk + 0][lr] = w0; Ws[lk + 1][lr] = w1; Ws[lk + 2][lr] = w2; Ws[lk + 3][lr] = w3;
        __syncthreads();
#pragma unroll
        for (int kk = 0; kk < 16; ++kk) {
            float4 av = *(const float4*)(&As[kk][ty << 2]);
            float4 wv = *(const float4*)(&Ws[kk][tx << 2]);
            float aa[4] = { av.x, av.y, av.z, av.w };
            float ww[4] = { wv.x, wv.y, wv.z, wv.w };
#pragma unroll
            for (int i = 0; i < 4; ++i)
#pragma unroll
                for (int j = 0; j < 4; ++j)
                    acc[i][j] = fmaf(aa[i], ww[j], acc[i][j]);
        }
    }

#pragma unroll
    for (int i = 0; i < 4; ++i) {
        const int row = m0 + (ty << 2) + i;
        if (row >= M) continue;
#pragma unroll
        for (int j = 0; j < 4; ++j) {
            const int col = n0 + (tx << 2) + j;
            if (col >= N) continue;
            float t = acc[i][j];
            if (bias) t += bias[col];
            if (act == 1) t = tanhfast(t);
            if (c_bf16) ((__hip_bfloat16*)Cv)[(size_t)row * N + col] = __float2bfloat16(t);
            else        ((float*)Cv)[(size_t)row * N + col] = t;
        }
    }
}

// ---------------------------------------------------------------------------
__global__ __launch_bounds__(256)
void transpose3(const float* __restrict__ Wu, const float* __restrict__ Wr,
                const float* __restrict__ Wf, float* __restrict__ Tu,
                float* __restrict__ Tr, float* __restrict__ Tf)
{
    int id = blockIdx.x * 256 + threadIdx.x;
    if (id >= 360000) return;
    int tab = id / 120000, r = id - tab * 120000;
    int e = r / 600, j = r - e * 600;
    const float* src = tab == 0 ? Wu : (tab == 1 ? Wr : Wf);
    float* dst = tab == 0 ? Tu : (tab == 1 ? Tr : Tf);
    dst[r] = src[(size_t)j * 200 + e];
}

// ---------------------------------------------------------------------------
__global__ __launch_bounds__(256)
void gather_re16(const int* __restrict__ resp, const float* __restrict__ emb,
                 __hip_bfloat16* __restrict__ re16)
{
    int idx = blockIdx.x * 256 + threadIdx.x;
    if (idx < 2560000) {
        int row = idx / 100, q = idx - row * 100;
        float2 v = *(const float2*)(emb + (size_t)resp[row] * 200 + 2 * q);
        ((unsigned*)re16)[idx] = packbf(v.x, v.y);
    }
}

// ---------------------------------------------------------------------------
// Persistent dual-GRU scan: 256 blocks x 512 thr, 50 steps.
// KEY: rg = tid%10 so the 10 lanes sharing a W float4 sit in the SAME wave
// (same-address coalescing) -> 10x less L1 traffic than rg = tid/50.
// ---------------------------------------------------------------------------
__global__ __launch_bounds__(512)
void scan_gru(const int* __restrict__ utt,
              const __hip_bfloat16* __restrict__ EPu,
              const __hip_bfloat16* __restrict__ xpr16,
              const float* __restrict__ WTu, const float* __restrict__ WTr,
              const float* __restrict__ bhu, const float* __restrict__ bhr,
              __hip_bfloat16* __restrict__ ug16,
              __hip_bfloat16* __restrict__ rg16)
{
    const int blk = blockIdx.x;          // 0..255
    const int tid = threadIdx.x;
    const int u0 = blk * 20;
    const int r0 = blk * 2;

    __shared__ float h[22][201];                       // rows 0..19 utt, 20..21 resp
    __shared__ __align__(16) __hip_bfloat16 xpu[20][600];
    __shared__ float xpr_s[2][600];

    for (int i = tid; i < 22 * 201; i += 512) ((float*)h)[i] = 0.0f;
    __syncthreads();

    const int rg = tid % 10;             // row-pair (lanes w/ same jg share W addr)
    const int jg = tid / 10;             // 0..49 col-group for tid<500
    const int j0 = 4 * jg;
    const int brr = tid & 1;             // resp row (2-lane W sharing)
    const int bj0 = 2 * (tid >> 1);      // 0..198 for tid<200

    for (int t = 0; t < 50; ++t) {
        // ---- stage x-projections ----
        for (int idx = tid; idx < 1500; idx += 512) {        // 20 rows x 75 uint4
            int row = idx / 75, q = idx - row * 75;
            int tok = utt[(u0 + row) * 50 + t];
            ((uint4*)&xpu[row][0])[q] = ((const uint4*)(EPu + (size_t)tok * 600))[q];
        }
        for (int idx = tid; idx < 600; idx += 512) {         // 2 rows x 300 uint
            int row = idx / 300, q = idx - row * 300;
            unsigned p = ((const unsigned*)(xpr16 + (size_t)((r0 + row) * 50 + t) * 600))[q];
            xpr_s[row][2 * q] = bl(p);
            xpr_s[row][2 * q + 1] = bh(p);
        }
        // ---- gh accumulation (reads h) ----
        float aR[2][4] = {}, aZ[2][4] = {}, aN[2][4] = {};
        if (tid < 500) {
            const int ra = 2 * rg, rb = 2 * rg + 1;
            for (int e = 0; e < 200; e += 4) {
                float4 wrv[4], wzv[4], wnv[4];
#pragma unroll
                for (int u = 0; u < 4; ++u) {
                    const float* w = WTu + (size_t)(e + u) * 600;
                    wrv[u] = *(const float4*)(w + j0);
                    wzv[u] = *(const float4*)(w + 200 + j0);
                    wnv[u] = *(const float4*)(w + 400 + j0);
                }
#pragma unroll
                for (int u = 0; u < 4; ++u) {
                    float h0 = h[ra][e + u], h1 = h[rb][e + u];
                    aR[0][0] = fmaf(h0, wrv[u].x, aR[0][0]); aR[0][1] = fmaf(h0, wrv[u].y, aR[0][1]);
                    aR[0][2] = fmaf(h0, wrv[u].z, aR[0][2]); aR[0][3] = fmaf(h0, wrv[u].w, aR[0][3]);
                    aZ[0][0] = fmaf(h0, wzv[u].x, aZ[0][0]); aZ[0][1] = fmaf(h0, wzv[u].y, aZ[0][1]);
                    aZ[0][2] = fmaf(h0, wzv[u].z, aZ[0][2]); aZ[0][3] = fmaf(h0, wzv[u].w, aZ[0][3]);
                    aN[0][0] = fmaf(h0, wnv[u].x, aN[0][0]); aN[0][1] = fmaf(h0, wnv[u].y, aN[0][1]);
                    aN[0][2] = fmaf(h0, wnv[u].z, aN[0][2]); aN[0][3] = fmaf(h0, wnv[u].w, aN[0][3]);
                    aR[1][0] = fmaf(h1, wrv[u].x, aR[1][0]); aR[1][1] = fmaf(h1, wrv[u].y, aR[1][1]);
                    aR[1][2] = fmaf(h1, wrv[u].z, aR[1][2]); aR[1][3] = fmaf(h1, wrv[u].w, aR[1][3]);
                    aZ[1][0] = fmaf(h1, wzv[u].x, aZ[1][0]); aZ[1][1] = fmaf(h1, wzv[u].y, aZ[1][1]);
                    aZ[1][2] = fmaf(h1, wzv[u].z, aZ[1][2]); aZ[1][3] = fmaf(h1, wzv[u].w, aZ[1][3]);
                    aN[1][0] = fmaf(h1, wnv[u].x, aN[1][0]); aN[1][1] = fmaf(h1, wnv[u].y, aN[1][1]);
                    aN[1][2] = fmaf(h1, wnv[u].z, aN[1][2]); aN[1][3] = fmaf(h1, wnv[u].w, aN[1][3]);
                }
            }
        }
        float bR[2] = {}, bZ[2] = {}, bN[2] = {};
        if (tid < 200) {
            for (int e = 0; e < 200; e += 4) {
                float2 wrv[4], wzv[4], wnv[4];
#pragma unroll
                for (int u = 0; u < 4; ++u) {
                    const float* w = WTr + (size_t)(e + u) * 600;
                    wrv[u] = *(const float2*)(w + bj0);
                    wzv[u] = *(const float2*)(w + 200 + bj0);
                    wnv[u] = *(const float2*)(w + 400 + bj0);
                }
#pragma unroll
                for (int u = 0; u < 4; ++u) {
                    float hv = h[20 + brr][e + u];
                    bR[0] = fmaf(hv, wrv[u].x, bR[0]); bR[1] = fmaf(hv, wrv[u].y, bR[1]);
                    bZ[0] = fmaf(hv, wzv[u].x, bZ[0]); bZ[1] = fmaf(hv, wzv[u].y, bZ[1]);
                    bN[0] = fmaf(hv, wnv[u].x, bN[0]); bN[1] = fmaf(hv, wnv[u].y, bN[1]);
                }
            }
        }
        __syncthreads();
        // ---- epilogue: gates, h update, archives ----
        if (tid < 500) {
            const int ra = 2 * rg;
#pragma unroll
            for (int i = 0; i < 2; ++i) {
                const int row = ra + i;
                float hn4[4];
#pragma unroll
                for (int j = 0; j < 4; ++j) {
                    const int c = j0 + j;
                    float xr = __bfloat162float(xpu[row][c]);
                    float xz = __bfloat162float(xpu[row][200 + c]);
                    float xn = __bfloat162float(xpu[row][400 + c]);
                    float rr = sigm(xr + aR[i][j] + bhu[c]);
                    float zz = sigm(xz + aZ[i][j] + bhu[200 + c]);
                    float nn = tanhfast(xn + rr * (aN[i][j] + bhu[400 + c]));
                    hn4[j] = (1.0f - zz) * nn + zz * h[row][c];
                }
#pragma unroll
                for (int j = 0; j < 4; ++j) h[row][j0 + j] = hn4[j];
                uint2 pk;
                pk.x = packbf(hn4[0], hn4[1]);
                pk.y = packbf(hn4[2], hn4[3]);
                *(uint2*)(ug16 + ((size_t)(u0 + row) * 50 + t) * 200 + j0) = pk;
            }
        }
        if (tid < 200) {
            const int row = 20 + brr;
            const int grow = r0 + brr;
#pragma unroll
            for (int j = 0; j < 2; ++j) {
                const int c = bj0 + j;
                float xr = xpr_s[brr][c];
                float xz = xpr_s[brr][200 + c];
                float xn = xpr_s[brr][400 + c];
                float rr = sigm(xr + bR[j] + bhr[c]);
                float zz = sigm(xz + bZ[j] + bhr[200 + c]);
                float nn = tanhfast(xn + rr * (bN[j] + bhr[400 + c]));
                float hn = (1.0f - zz) * nn + zz * h[row][c];
                h[row][c] = hn;
                rg16[((size_t)grow * 50 + t) * 200 + c] = __float2bfloat16(hn);
            }
        }
        __syncthreads();
    }
}

// ---------------------------------------------------------------------------
// Fused m1/m2 match + conv3x3(2->8)+relu+maxpool3x3 per (b,u).
// ---------------------------------------------------------------------------
__global__ __launch_bounds__(256)
void match_conv_pool(const int* __restrict__ utt, const float* __restrict__ emb,
                     const __hip_bfloat16* __restrict__ ug16,
                     const __hip_bfloat16* __restrict__ re16,
                     const __hip_bfloat16* __restrict__ rgA16,
                     const float* __restrict__ cw, const float* __restrict__ cb,
                     float* __restrict__ pooled)
{
    const int bu = blockIdx.x, b = bu / 10;
    __shared__ __hip_bfloat16 As[50][204];
    __shared__ __hip_bfloat16 Bs[50][204];
    __shared__ float m[2][50][50];
    __shared__ float w[144];
    __shared__ float bsh[8];
    const int tid = threadIdx.x;
    if (tid < 144) w[tid] = cw[tid];
    if (tid >= 144 && tid < 152) bsh[tid - 144] = cb[tid - 144];

    for (int idx = tid; idx < 5000; idx += 256) {
        int l = idx / 100, q = idx - l * 100;
        int tok = utt[bu * 50 + l];
        float2 v = *(const float2*)(emb + (size_t)tok * 200 + 2 * q);
        *(unsigned*)&As[l][2 * q] = packbf(v.x, v.y);
        *(unsigned*)&Bs[l][2 * q] =
            ((const unsigned*)(re16 + (size_t)b * 10000 + (size_t)l * 200))[q];
    }
    __syncthreads();
#pragma unroll 1
    for (int ch = 0; ch < 2; ++ch) {
        for (int task = tid; task < 625; task += 256) {
            int lq = task / 25, tq = task - lq * 25;
            float s00 = 0, s01 = 0, s10 = 0, s11 = 0;
#pragma unroll 4
            for (int q = 0; q < 100; ++q) {
                unsigned a0 = *(const unsigned*)&As[lq][2 * q];
                unsigned a1 = *(const unsigned*)&As[lq + 25][2 * q];
                unsigned b0 = *(const unsigned*)&Bs[tq][2 * q];
                unsigned b1 = *(const unsigned*)&Bs[tq + 25][2 * q];
                float a0l = bl(a0), a0h = bh(a0), a1l = bl(a1), a1h = bh(a1);
                float b0l = bl(b0), b0h = bh(b0), b1l = bl(b1), b1h = bh(b1);
                s00 = fmaf(a0l, b0l, fmaf(a0h, b0h, s00));
                s01 = fmaf(a0l, b1l, fmaf(a0h, b1h, s01));
                s10 = fmaf(a1l, b0l, fmaf(a1h, b0h, s10));
                s11 = fmaf(a1l, b1l, fmaf(a1h, b1h, s11));
            }
            m[ch][lq][tq] = s00;           m[ch][lq][tq + 25] = s01;
            m[ch][lq + 25][tq] = s10;      m[ch][lq + 25][tq + 25] = s11;
        }
        __syncthreads();
        if (ch == 0) {
            for (int idx = tid; idx < 5000; idx += 256) {
                int l = idx / 100, q = idx - l * 100;
                *(unsigned*)&As[l][2 * q] =
                    ((const unsigned*)(ug16 + (size_t)bu * 10000 + (size_t)l * 200))[q];
                *(unsigned*)&Bs[l][2 * q] =
                    ((const unsigned*)(rgA16 + (size_t)b * 10000 + (size_t)l * 200))[q];
            }
            __syncthreads();
        }
    }
#pragma unroll
    for (int k = 0; k < 8; ++k) {
        const int o = tid + k * 256;
        const int c = o >> 8, ph = (o >> 4) & 15, pw = o & 15;
        float mx = -1e30f;
#pragma unroll
        for (int p = 0; p < 3; ++p)
#pragma unroll
            for (int q = 0; q < 3; ++q) {
                const int y = ph * 3 + p, x = pw * 3 + q;
                float s = bsh[c];
#pragma unroll
                for (int ci = 0; ci < 2; ++ci)
#pragma unroll
                    for (int dy = 0; dy < 3; ++dy)
#pragma unroll
                        for (int dx = 0; dx < 3; ++dx)
                            s = fmaf(w[(c * 2 + ci) * 9 + dy * 3 + dx],
                                     m[ci][y + dy][x + dx], s);
                s = fmaxf(s, 0.0f);
                mx = fmaxf(mx, s);
            }
        pooled[(size_t)bu * 2048 + o] = mx;
    }
}

// ---------------------------------------------------------------------------
__global__ __launch_bounds__(256)
void final_gru(const float* __restrict__ xpf, const float* __restrict__ WTf,
               const float* __restrict__ bhf, const float* __restrict__ fw,
               const float* __restrict__ fb, float* __restrict__ out)
{
    const int blk = blockIdx.x;
    const int tid = threadIdx.x;
    __shared__ float h[2][201];
    for (int i = tid; i < 402; i += 256) ((float*)h)[i] = 0.0f;
    __syncthreads();
    const int rr = tid / 100;
    const int j0 = 2 * (tid % 100);
    for (int t = 0; t < 10; ++t) {
        float cR[2] = {}, cZ[2] = {}, cN[2] = {};
        if (tid < 200) {
#pragma unroll 2
            for (int e = 0; e < 200; ++e) {
                const float* w = WTf + (size_t)e * 600;
                float2 wr = *(const float2*)(w + j0);
                float2 wz = *(const float2*)(w + 200 + j0);
                float2 wn = *(const float2*)(w + 400 + j0);
                float hv = h[rr][e];
                cR[0] = fmaf(hv, wr.x, cR[0]); cR[1] = fmaf(hv, wr.y, cR[1]);
                cZ[0] = fmaf(hv, wz.x, cZ[0]); cZ[1] = fmaf(hv, wz.y, cZ[1]);
                cN[0] = fmaf(hv, wn.x, cN[0]); cN[1] = fmaf(hv, wn.y, cN[1]);
            }
        }
        __syncthreads();
        if (tid < 200) {
            const float* xp = xpf + ((size_t)(blk * 2 + rr) * 10 + t) * 600;
#pragma unroll
            for (int j = 0; j < 2; ++j) {
                const int c = j0 + j;
                float rrg = sigm(xp[c] + cR[j] + bhf[c]);
                float zz = sigm(xp[200 + c] + cZ[j] + bhf[200 + c]);
                float nn = tanhfast(xp[400 + c] + rrg * (cN[j] + bhf[400 + c]));
                h[rr][c] = (1.0f - zz) * nn + zz * h[rr][c];
            }
        }
        __syncthreads();
    }
    if (tid < 2) {
        float s = fb[0];
        for (int k = 0; k < 200; ++k) s = fmaf(h[tid][k], fw[k], s);
        out[blk * 2 + tid] = sigm(s);
    }
}

__global__ __launch_bounds__(256)
void fill_out(float* __restrict__ out)
{
    int i = blockIdx.x * 256 + threadIdx.x;
    if (i < 512) out[i] = 0.0f;
}

// ---------------------------------------------------------------------------
extern "C" void kernel_launch(void* const* d_in, const int* in_sizes, int n_in,
                              void* d_out, int out_size, void* d_ws, size_t ws_size,
                              hipStream_t stream)
{
    const int*   utt    = (const int*)d_in[0];
    const int*   resp   = (const int*)d_in[1];
    const float* emb    = (const float*)d_in[2];
    const float* W_ih_u = (const float*)d_in[3];
    const float* W_hh_u = (const float*)d_in[4];
    const float* b_ih_u = (const float*)d_in[5];
    const float* b_hh_u = (const float*)d_in[6];
    const float* W_ih_r = (const float*)d_in[7];
    const float* W_hh_r = (const float*)d_in[8];
    const float* b_ih_r = (const float*)d_in[9];
    const float* b_hh_r = (const float*)d_in[10];
    const float* conv_w = (const float*)d_in[11];
    const float* conv_b = (const float*)d_in[12];
    const float* lin_w  = (const float*)d_in[13];
    const float* lin_b  = (const float*)d_in[14];
    const float* Amat   = (const float*)d_in[15];
    const float* W_ih_f = (const float*)d_in[16];
    const float* W_hh_f = (const float*)d_in[17];
    const float* b_ih_f = (const float*)d_in[18];
    const float* b_hh_f = (const float*)d_in[19];
    const float* flin_w = (const float*)d_in[20];
    const float* flin_b = (const float*)d_in[21];
    float* out = (float*)d_out;
    float* ws  = (float*)d_ws;

    size_t off = 0;
    auto alloc = [&](size_t n) { float* p = ws + off; off += (n + 63) & ~((size_t)63); return p; };
    float* WT_u   = alloc(120000);
    float* WT_r   = alloc(120000);
    float* WT_f   = alloc(120000);
    float* re16f  = alloc(2560000);    // [25600,200] bf16
    float* EPuf   = alloc(15000000);   // [50000,600] bf16; post-scan: pooled
    float* xprf   = alloc(7680000);    // [25600,600] bf16; post-scan: mv/xpf
    float* ug16f  = alloc(25600000);   // [5120,50,200] bf16
    float* rg16f  = alloc(2560000);    // [512,50,200] bf16
    float* rgA16f = alloc(2560000);    // [25600,200] bf16
    // total 56.32M floats = 225 MB

    if (off * sizeof(float) > ws_size) {
        hipLaunchKernelGGL(fill_out, dim3(2), dim3(256), 0, stream, out);
        return;
    }

    __hip_bfloat16* re16  = (__hip_bfloat16*)re16f;
    __hip_bfloat16* EPu   = (__hip_bfloat16*)EPuf;
    __hip_bfloat16* xpr16 = (__hip_bfloat16*)xprf;
    __hip_bfloat16* ug16  = (__hip_bfloat16*)ug16f;
    __hip_bfloat16* rg16  = (__hip_bfloat16*)rg16f;
    __hip_bfloat16* rgA16 = (__hip_bfloat16*)rgA16f;
    float* pooled = EPuf;              // [5120,2048] f32 (EPu dead after scan)
    float* mv     = xprf;              // [5120,50] f32  (xpr dead after scan)
    float* xpf    = xprf + 400000;     // [5120,600] f32

    // 1. weight transposes (f32, for the scan / final GRU)
    hipLaunchKernelGGL(transpose3, dim3(1407), dim3(256), 0, stream,
                       W_hh_u, W_hh_r, W_hh_f, WT_u, WT_r, WT_f);
    // 2. response embedding gather (bf16)
    hipLaunchKernelGGL(gather_re16, dim3(10000), dim3(256), 0, stream, resp, emb, re16);
    // 3. EPu = bf16(emb @ W_ih_u^T + b_ih_u) for the whole vocab  [MFMA]
    hipLaunchKernelGGL(gemm_mfma, dim3(782, 10), dim3(256), 0, stream,
                       (const void*)emb, 0, (const int*)nullptr, W_ih_u, b_ih_u,
                       EPu, 50000, 600);
    // 4. xpr16 = bf16(emb[resp] @ W_ih_r^T + b_ih_r)  [MFMA]
    hipLaunchKernelGGL(gemm_mfma, dim3(400, 10), dim3(256), 0, stream,
                       (const void*)emb, 0, resp, W_ih_r, b_ih_r,
                       xpr16, 25600, 600);
    // 5. persistent dual-GRU scan
    hipLaunchKernelGGL(scan_gru, dim3(256), dim3(512), 0, stream,
                       utt, EPu, xpr16, WT_u, WT_r, b_hh_u, b_hh_r, ug16, rg16);
    // 6. rgA16 = bf16(rg @ Amat^T)  [MFMA]
    hipLaunchKernelGGL(gemm_mfma, dim3(400, 4), dim3(256), 0, stream,
                       (const void*)rg16, 1, (const int*)nullptr, Amat,
                       (const float*)nullptr, rgA16, 25600, 200);
    // 7. fused match + conv + pool
    hipLaunchKernelGGL(match_conv_pool, dim3(5120), dim3(256), 0, stream,
                       utt, emb, ug16, re16, rgA16, conv_w, conv_b, pooled);
    // 8. mv = tanh(pooled @ lin_w^T + lin_b)
    hipLaunchKernelGGL(gemm_tn, dim3(80, 1), dim3(256), 0, stream,
                       pooled, 0, (const int*)nullptr, 1, 0, lin_w, lin_b,
                       mv, 0, 5120, 50, 2048, 1);
    // 9. xpf = mv @ W_ih_f^T + b_ih_f
    hipLaunchKernelGGL(gemm_tn, dim3(80, 10), dim3(256), 0, stream,
                       mv, 0, (const int*)nullptr, 1, 0, W_ih_f, b_ih_f,
                       xpf, 0, 5120, 600, 50, 0);
    // 10. final GRU + logit + sigmoid
    hipLaunchKernelGGL(final_gru, dim3(256), dim3(256), 0, stream,
                       xpf, WT_f, b_hh_f, flin_w, flin_b, out);
}